// Round 2
// baseline (1219.915 us; speedup 1.0000x reference)
//
#include <hip/hip_runtime.h>
#include <math.h>

// Problem constants (fixed by the reference)
#define B_    64
#define LOOKB 32
#define NS    256
#define DM    512
#define DK    128
#define DV    128

__device__ __forceinline__ float sigmoidf_(float x) {
    return 1.0f / (1.0f + expf(-x));
}

// max_lag arrives as a 1-element array; Python int -> int32, but be robust to
// a float32 encoding too (bits of 16.0f are >= 2^23, so this disambiguates).
__device__ __forceinline__ float load_maxlag(const void* p) {
    int vi = *(const int*)p;
    if (vi >= 0 && vi < (1 << 23)) return (float)vi;
    return *(const float*)p;
}

__device__ __forceinline__ void lag_params(const float* __restrict__ lags,
                                           float maxlag, int s,
                                           int& lf, int& lc, float& alpha) {
    float lag = sigmoidf_(lags[s]) * maxlag;
    float lf_f = fminf(fmaxf(floorf(lag), 0.0f), (float)(LOOKB - 1));
    float lc_f = fminf(fmaxf(ceilf(lag), 0.0f), (float)(LOOKB - 1));
    lf = (int)lf_f;
    lc = (int)lc_f;
    alpha = lag - lf_f;
}

// ---------------------------------------------------------------------------
// K0: m[b,d] = sum_k q[b,k] * W_k[k,d],  q[b,k] = sum_d' query[b,d'] * W_q[k,d']
// grid: B_ blocks x 256 threads
// ---------------------------------------------------------------------------
__global__ void k_prep(const float* __restrict__ query,
                       const float* __restrict__ Wq,
                       const float* __restrict__ Wk,
                       float* __restrict__ ws_m) {
    __shared__ float qe[DM];
    __shared__ float qv[DK];
    const int b = blockIdx.x;
    const int tid = threadIdx.x;

    qe[tid]       = query[b * DM + tid];
    qe[tid + 256] = query[b * DM + tid + 256];
    __syncthreads();

    if (tid < DK) {
        const float4* wr = (const float4*)(Wq + (size_t)tid * DM);
        const float4* qr = (const float4*)qe;
        float acc = 0.f;
#pragma unroll 8
        for (int i = 0; i < DM / 4; ++i) {
            float4 w = wr[i], q4 = qr[i];
            acc += w.x * q4.x + w.y * q4.y + w.z * q4.z + w.w * q4.w;
        }
        qv[tid] = acc;
    }
    __syncthreads();

    // coalesced across d: thread t handles d = t, t+256
    for (int d = tid; d < DM; d += 256) {
        float acc = 0.f;
#pragma unroll 8
        for (int k = 0; k < DK; ++k)
            acc += qv[k] * Wk[(size_t)k * DM + d];
        ws_m[b * DM + d] = acc;
    }
}

// ---------------------------------------------------------------------------
// KA: scores[b,s] = gate[s] * (m[b] . interp_emb[b,s]) / sqrt(DK)
// One wave per (b,s); 4 waves/block share b. grid: B_*64 blocks x 256 thr.
// Each lane loads 8 floats (2x float4) of each of the two gathered rows.
// ---------------------------------------------------------------------------
__global__ void k_scores(const float* __restrict__ embs,
                         const float* __restrict__ lags,
                         const float* __restrict__ gates,
                         const void*  __restrict__ maxlag_p,
                         const float* __restrict__ ws_m,
                         float* __restrict__ ws_scores) {
    const int tid  = threadIdx.x;
    const int b     = blockIdx.x >> 6;
    const int sbase = (blockIdx.x & 63) << 2;
    const int wave  = tid >> 6;
    const int lane  = tid & 63;
    const int s     = sbase + wave;

    const float maxlag = load_maxlag(maxlag_p);
    int lf, lc; float alpha;
    lag_params(lags, maxlag, s, lf, lc, alpha);
    const float gate = sigmoidf_(gates[s]);

    const size_t off = (size_t)lane * 8;
    const float* mrow = ws_m + (size_t)b * DM + off;
    float4 m0 = *(const float4*)(mrow);
    float4 m1 = *(const float4*)(mrow + 4);

    const size_t bf = (((size_t)b * LOOKB + lf) * NS + s) * (size_t)DM + off;
    const size_t bc = (((size_t)b * LOOKB + lc) * NS + s) * (size_t)DM + off;
    float4 f0 = *(const float4*)(embs + bf);
    float4 f1 = *(const float4*)(embs + bf + 4);
    float4 c0 = *(const float4*)(embs + bc);
    float4 c1 = *(const float4*)(embs + bc + 4);

    float acc = m0.x * (f0.x + alpha * (c0.x - f0.x))
              + m0.y * (f0.y + alpha * (c0.y - f0.y))
              + m0.z * (f0.z + alpha * (c0.z - f0.z))
              + m0.w * (f0.w + alpha * (c0.w - f0.w))
              + m1.x * (f1.x + alpha * (c1.x - f1.x))
              + m1.y * (f1.y + alpha * (c1.y - f1.y))
              + m1.z * (f1.z + alpha * (c1.z - f1.z))
              + m1.w * (f1.w + alpha * (c1.w - f1.w));

#pragma unroll
    for (int off2 = 32; off2; off2 >>= 1)
        acc += __shfl_xor(acc, off2, 64);

    if (lane == 0)
        ws_scores[b * NS + s] = gate * acc * 0.0883883476483184405f; // 1/sqrt(128)
}

// ---------------------------------------------------------------------------
// KC (softmax fused): each block recomputes the b-row softmax normalizers
// from ws_scores (cheap: 256 L2-resident floats), then accumulates
// partial ctx_d[b,d] = sum_{s in chunk of 32} attn[b,s] * interp_emb[b,s,d].
// grid: B_*8 blocks x 256 thr (4 waves). Wave w handles 8 stocks; each lane
// owns 8 floats of d (2x float4, 16B/lane loads). Cross-wave LDS reduce,
// then one float2-per-thread coalesced partial write.
// ---------------------------------------------------------------------------
__global__ void k_ctx(const float* __restrict__ embs,
                      const float* __restrict__ lags,
                      const void*  __restrict__ maxlag_p,
                      const float* __restrict__ ws_scores,
                      float* __restrict__ ws_part) {
    __shared__ float rred[8];          // 4 max, 4 sum
    __shared__ float attn_sm[32];
    __shared__ int   lf_sm[32];
    __shared__ int   lc_sm[32];
    __shared__ float al_sm[32];
    __shared__ float red[4][DM];       // 8 KB cross-wave reduction

    const int b     = blockIdx.x >> 3;
    const int chunk = blockIdx.x & 7;
    const int tid   = threadIdx.x;
    const int wave  = tid >> 6;
    const int lane  = tid & 63;
    const float maxlag = load_maxlag(maxlag_p);
    const int s0 = chunk * 32;

    // --- block-redundant softmax normalizers over all 256 scores of b ---
    float v = ws_scores[b * NS + tid];
    float mx = v;
#pragma unroll
    for (int o = 32; o; o >>= 1) mx = fmaxf(mx, __shfl_xor(mx, o, 64));
    if (lane == 0) rred[wave] = mx;
    __syncthreads();
    mx = fmaxf(fmaxf(rred[0], rred[1]), fmaxf(rred[2], rred[3]));
    float e = expf(v - mx);
    float sm = e;
#pragma unroll
    for (int o = 32; o; o >>= 1) sm += __shfl_xor(sm, o, 64);
    if (lane == 0) rred[4 + wave] = sm;
    __syncthreads();
    const float tot = rred[4] + rred[5] + rred[6] + rred[7];

    // --- per-stock attn + lag params for this chunk ---
    if (tid < 32) {
        const int s = s0 + tid;
        attn_sm[tid] = expf(ws_scores[b * NS + s] - mx) / tot;
        int lf, lc; float alpha;
        lag_params(lags, maxlag, s, lf, lc, alpha);
        lf_sm[tid] = lf; lc_sm[tid] = lc; al_sm[tid] = alpha;
    }
    __syncthreads();

    // --- gather + weighted accumulate: wave w -> stocks [w*8, w*8+8) ---
    const size_t doff = (size_t)lane * 8;
    float4 a0 = {0.f, 0.f, 0.f, 0.f}, a1 = {0.f, 0.f, 0.f, 0.f};
#pragma unroll
    for (int i = 0; i < 8; ++i) {
        const int sl = wave * 8 + i;
        const int s  = s0 + sl;
        const float w   = attn_sm[sl];
        const float al  = al_sm[sl];
        const float wf  = w * (1.0f - al);
        const float wc  = w * al;
        const size_t bf = (((size_t)b * LOOKB + lf_sm[sl]) * NS + s) * (size_t)DM + doff;
        const size_t bc = (((size_t)b * LOOKB + lc_sm[sl]) * NS + s) * (size_t)DM + doff;
        float4 f0 = *(const float4*)(embs + bf);
        float4 f1 = *(const float4*)(embs + bf + 4);
        float4 c0 = *(const float4*)(embs + bc);
        float4 c1 = *(const float4*)(embs + bc + 4);
        a0.x += wf * f0.x + wc * c0.x;  a0.y += wf * f0.y + wc * c0.y;
        a0.z += wf * f0.z + wc * c0.z;  a0.w += wf * f0.w + wc * c0.w;
        a1.x += wf * f1.x + wc * c1.x;  a1.y += wf * f1.y + wc * c1.y;
        a1.z += wf * f1.z + wc * c1.z;  a1.w += wf * f1.w + wc * c1.w;
    }

    // --- cross-wave reduce in LDS, then coalesced partial write ---
    *(float4*)(&red[wave][doff])     = a0;
    *(float4*)(&red[wave][doff + 4]) = a1;
    __syncthreads();

    const int d0 = tid * 2;
    float sx = red[0][d0]     + red[1][d0]     + red[2][d0]     + red[3][d0];
    float sy = red[0][d0 + 1] + red[1][d0 + 1] + red[2][d0 + 1] + red[3][d0 + 1];
    float2 outv; outv.x = sx; outv.y = sy;
    *(float2*)(ws_part + ((size_t)(b * 8 + chunk)) * DM + d0) = outv;
}

// ---------------------------------------------------------------------------
// KD: ctx_d[b] = sum of 8 partials; out[b,v] = W_v[v,:] . ctx_d[b]
// grid: B_ blocks x 128 threads (one per v)
// ---------------------------------------------------------------------------
__global__ void k_out(const float* __restrict__ ws_part,
                      const float* __restrict__ Wv,
                      float* __restrict__ out) {
    __shared__ float ctx[DM];
    const int b = blockIdx.x, tid = threadIdx.x;

    for (int d = tid; d < DM; d += 128) {
        float a = 0.f;
#pragma unroll
        for (int c = 0; c < 8; ++c)
            a += ws_part[((size_t)(b * 8 + c)) * DM + d];
        ctx[d] = a;
    }
    __syncthreads();

    const float4* wr = (const float4*)(Wv + (size_t)tid * DM);
    const float4* cr = (const float4*)ctx;
    float acc = 0.f;
#pragma unroll 8
    for (int i = 0; i < DM / 4; ++i) {
        float4 w = wr[i], c = cr[i];
        acc += w.x * c.x + w.y * c.y + w.z * c.z + w.w * c.w;
    }
    out[b * DV + tid] = acc;
}

// ---------------------------------------------------------------------------
extern "C" void kernel_launch(void* const* d_in, const int* in_sizes, int n_in,
                              void* d_out, int out_size, void* d_ws, size_t ws_size,
                              hipStream_t stream) {
    const float* query = (const float*)d_in[0];   // (B, DM)
    const float* embs  = (const float*)d_in[1];   // (B, LOOKB, NS, DM)
    const float* Wq    = (const float*)d_in[2];   // (DK, DM)
    const float* Wk    = (const float*)d_in[3];   // (DK, DM)
    const float* Wv    = (const float*)d_in[4];   // (DV, DM)
    const float* lags  = (const float*)d_in[5];   // (NS,)
    const float* gates = (const float*)d_in[6];   // (NS,)
    const void*  maxlag_p = d_in[7];              // scalar

    float* out = (float*)d_out;                   // (B, DV) fp32

    // Workspace layout (floats): m | scores | partials
    float* ws        = (float*)d_ws;
    float* ws_m      = ws;                        // B*DM      = 32768
    float* ws_scores = ws + 32768;                // B*NS      = 16384
    float* ws_part   = ws + 65536;                // B*8*DM    = 262144
    (void)in_sizes; (void)n_in; (void)out_size; (void)ws_size;

    k_prep<<<B_, 256, 0, stream>>>(query, Wq, Wk, ws_m);
    k_scores<<<B_ * 64, 256, 0, stream>>>(embs, lags, gates, maxlag_p, ws_m, ws_scores);
    k_ctx<<<B_ * 8, 256, 0, stream>>>(embs, lags, maxlag_p, ws_scores, ws_part);
    k_out<<<B_, 128, 0, stream>>>(ws_part, Wv, out);
}